// Round 13
// baseline (2161.077 us; speedup 1.0000x reference)
//
#include <hip/hip_runtime.h>

#define NB 16
#define NN 8192
#define NS 1024
#define NK 32
#define NR (NB*NS*NK)   // 524288 rows through the MLP

static __device__ __forceinline__ int brev6(int l) {
  return ((l&1)<<5)|((l&2)<<3)|((l&4)<<1)|((l&8)>>1)|((l&16)>>3)|((l&32)>>5);
}

// pack two f32 -> two bf16 (RNE) in one uint (low = first)
static __device__ __forceinline__ unsigned pack_bf2(float a, float b) {
  unsigned ua = __float_as_uint(a), ub = __float_as_uint(b);
  ua += 0x7fffu + ((ua >> 16) & 1u);
  ub += 0x7fffu + ((ub >> 16) & 1u);
  return (ua >> 16) | (ub & 0xffff0000u);
}
static __device__ __forceinline__ float bf_lo(unsigned u) { return __uint_as_float(u << 16); }
static __device__ __forceinline__ float bf_hi(unsigned u) { return __uint_as_float(u & 0xffff0000u); }

// ---------------------------------------------------------------------------
// FPS v7: SCALAR intrinsic arithmetic only (r10/r12 lesson: every packed-f32
// variant changed decisions; __fmul_rn/__fadd_rn is the proven-passing form).
// Re-tiled for occupancy: 1024 thr (16 waves, 4/SIMD), 8 pts/thread.
// Cheap argmax (f32 shuffle-max + equality scan + ballot min-index resolve,
// exact first-index tie-break), LDS xyz mirror, one barrier/step.
// ---------------------------------------------------------------------------
__global__ __launch_bounds__(1024, 1) void fps_kernel(const float* __restrict__ xyz,
                                                      float* __restrict__ new_xyz) {
  const int b = blockIdx.x;
  const int t = threadIdx.x;            // 0..1023
  const int lane = t & 63;
  const int wv = t >> 6;                // 0..15
  const float* base = xyz + (size_t)b * NN * 3;

  __shared__ float sx[NN], sy[NN], sz[NN];      // 96 KB mirror
  __shared__ unsigned long long s_wb[2][16];    // [parity][wave]

  float px[8], py[8], pz[8], dist[8];
#pragma unroll
  for (int j = 0; j < 8; ++j) {
    int p = j * 1024 + t;
    float x = base[p*3+0], y = base[p*3+1], z = base[p*3+2];
    px[j] = x; py[j] = y; pz[j] = z; dist[j] = 1e10f;
    sx[p] = x; sy[p] = y; sz[p] = z;
  }
  __syncthreads();

  float cx = sx[0], cy = sy[0], cz = sz[0];
  float* outp = new_xyz + (size_t)b * NS * 3;
  if (t == 0) { outp[0] = cx; outp[1] = cy; outp[2] = cz; }

  for (int s = 1; s < NS; ++s) {
    const int par = s & 1;
    float bestv = -1.0f;
#pragma unroll
    for (int j = 0; j < 8; ++j) {
      float dx = px[j]-cx, dy = py[j]-cy, dz = pz[j]-cz;
      // exact numpy order: (dx*dx + dy*dy) + dz*dz, no contraction possible
      float d = __fadd_rn(__fadd_rn(__fmul_rn(dx,dx),__fmul_rn(dy,dy)),__fmul_rn(dz,dz));
      float nd = fminf(dist[j], d);
      dist[j] = nd;
      bestv = fmaxf(bestv, nd);
    }
    // wave max (f32 butterfly)
    float wmax = bestv;
#pragma unroll
    for (int off = 32; off >= 1; off >>= 1)
      wmax = fmaxf(wmax, __shfl_xor(wmax, off, 64));
    // smallest matching j in this lane (descending overwrite scan)
    int minj = 0;
#pragma unroll
    for (int j = 7; j >= 0; --j) if (dist[j] == wmax) minj = j;
    const int myidx = minj * 1024 + t;
    // resolve min index among lanes attaining wmax
    const unsigned long long mask = __ballot(bestv == wmax);
    int l0 = __ffsll((unsigned long long)mask) - 1;
    int widx = __shfl(myidx, l0, 64);
    if (__popcll(mask) > 1) {                    // wave-uniform rare path
      unsigned long long m = mask & (mask - 1);
      while (m) {
        int l = __ffsll((unsigned long long)m) - 1;
        int v = __shfl(myidx, l, 64);
        widx = min(widx, v);
        m &= m - 1;
      }
    }
    if (lane == 0)
      s_wb[par][wv] = ((unsigned long long)__float_as_uint(wmax) << 32)
                      | (unsigned)(8191 - widx);
    __syncthreads();                             // the only barrier per step
    unsigned long long gk = s_wb[par][0];
#pragma unroll
    for (int i = 1; i < 16; ++i) {
      unsigned long long ki = s_wb[par][i]; if (ki > gk) gk = ki;
    }
    const int bi = 8191 - (int)(gk & 0xffffull);
    cx = sx[bi]; cy = sy[bi]; cz = sz[bi];
    if (t == 0) {
      float* o = outp + s*3;
      o[0] = cx; o[1] = cy; o[2] = cz;
    }
  }
}

// ---------------------------------------------------------------------------
// Ball query + gather + concat (unchanged, PASSES).
// ---------------------------------------------------------------------------
__global__ __launch_bounds__(256) void ballquery_kernel(const float* __restrict__ xyz,
                                                        const float* __restrict__ pts,
                                                        const float* __restrict__ new_xyz,
                                                        float* __restrict__ x0) {
  const int gw = ((blockIdx.x << 8) + threadIdx.x) >> 6;
  const int lane = threadIdx.x & 63;
  const int b = gw >> 10;
  const float* base = xyz + (size_t)b * NN * 3;
  const float* pbase = pts + (size_t)b * NN * 3;
  const float* cp = new_xyz + (size_t)gw * 3;
  const float cx = cp[0], cy = cp[1], cz = cp[2];
  const float t1 = __fadd_rn(__fadd_rn(__fmul_rn(cx,cx),__fmul_rn(cy,cy)),__fmul_rn(cz,cz));
  const float R2 = 0.04f;
  float* out = x0 + (size_t)gw * (NK*6);

  int count = 0, pfirst = 0;
  for (int n0 = 0; n0 < NN; n0 += 64) {
    const int p = n0 + lane;
    const float ax = base[p*3], ay = base[p*3+1], az = base[p*3+2];
    const float t2 = __fadd_rn(__fadd_rn(__fmul_rn(ax,ax),__fmul_rn(ay,ay)),__fmul_rn(az,az));
    const float dt = __fmaf_rn(cz, az, __fmaf_rn(cy, ay, __fmul_rn(cx, ax)));
    const float sq = __fadd_rn(__fsub_rn(t1, __fmul_rn(2.0f,dt)), t2);
    const bool keep = !(sq > R2);
    const unsigned long long mask = __ballot(keep);
    const int slot = count + __popcll(mask & ((1ull<<lane)-1ull));
    if (keep && slot < NK) {
      float* o = out + slot*6;
      o[0]=ax-cx; o[1]=ay-cy; o[2]=az-cz;
      o[3]=pbase[p*3]; o[4]=pbase[p*3+1]; o[5]=pbase[p*3+2];
    }
    if (count == 0 && mask != 0ull) pfirst = n0 + (__ffsll((unsigned long long)mask) - 1);
    count += __popcll(mask);
    if (count >= NK) break;
  }
  if (count < NK) {
    const float* fx = base + (size_t)pfirst*3;
    const float* fp = pbase + (size_t)pfirst*3;
    const float a0 = fx[0]-cx, a1 = fx[1]-cy, a2 = fx[2]-cz;
    const float a3 = fp[0], a4 = fp[1], a5 = fp[2];
    for (int sl = count + lane; sl < NK; sl += 64) {
      float* o = out + sl*6;
      o[0]=a0;o[1]=a1;o[2]=a2;o[3]=a3;o[4]=a4;o[5]=a5;
    }
  }
}

// ---------------------------------------------------------------------------
// butterfly64: z[0] = wave sum of channel brev6(lane).
// ---------------------------------------------------------------------------
__device__ __forceinline__ void butterfly64(float (&z)[64], float (&q)[64], int lane) {
#pragma unroll
  for (int d = 0; d < 6; ++d) {
    const int m = 32 >> d;
    const bool hi = (lane >> d) & 1;
#pragma unroll
    for (int i = 0; i < m; ++i) {
      float sv = hi ? z[i] : z[i+m];
      float rv = __shfl_xor(sv, 1<<d, 64);
      z[i] = (hi ? z[i+m] : z[i]) + rv;
      float sq = hi ? q[i] : q[i+m];
      float rq = __shfl_xor(sq, 1<<d, 64);
      q[i] = (hi ? q[i+m] : q[i]) + rq;
    }
  }
}

// ---------------------------------------------------------------------------
// BN finalize (nrows = block count, 4x smaller than wave count).
// ---------------------------------------------------------------------------
__global__ __launch_bounds__(256) void finalize_kernel(const float* __restrict__ part,
                                                       int nrows, int rowstride, int C,
                                                       const float* __restrict__ g,
                                                       const float* __restrict__ be,
                                                       float* __restrict__ ab) {
  const int ch = blockIdx.x;
  const int t = threadIdx.x;
  const int qo = rowstride >> 1;
  double s = 0.0, q = 0.0;
  for (int wv = t; wv < nrows; wv += 256) {
    s += (double)part[(size_t)wv*rowstride + ch];
    q += (double)part[(size_t)wv*rowstride + qo + ch];
  }
#pragma unroll
  for (int off = 32; off >= 1; off >>= 1) {
    s += __shfl_down(s, off, 64);
    q += __shfl_down(q, off, 64);
  }
  __shared__ double ls[4], lq[4];
  if ((t & 63) == 0) { ls[t>>6] = s; lq[t>>6] = q; }
  __syncthreads();
  if (t == 0) {
    double S = ls[0]+ls[1]+ls[2]+ls[3];
    double Q = lq[0]+lq[1]+lq[2]+lq[3];
    double mean = S / (double)NR;
    double var  = Q / (double)NR - mean*mean;
    double inv  = 1.0 / sqrt(var + 1e-5);
    double gg   = (double)g[ch];
    ab[ch]     = (float)(gg * inv);
    ab[C + ch] = (float)((double)be[ch] - mean * gg * inv);
  }
}

// ============================ MLP passes ============================
// Each block (4 waves) LDS-reduces its 4 wave-partials -> ONE part row per
// block (coalesced write); finalize's strided read shrinks 4x.

__global__ __launch_bounds__(256) void stats1_kernel(const float* __restrict__ x0,
                                                     const float* __restrict__ w,
                                                     const float* __restrict__ bias,
                                                     float* __restrict__ part) {
  const int r = blockIdx.x * 256 + threadIdx.x;
  const int lane = threadIdx.x & 63;
  const int wvi = threadIdx.x >> 6;
  __shared__ float red[4][128];
  const float* xr = x0 + (size_t)r * 6;
  float x[6];
#pragma unroll
  for (int c = 0; c < 6; ++c) x[c] = xr[c];
  float z[64];
#pragma unroll
  for (int o = 0; o < 64; ++o) {
    float acc = bias[o];
#pragma unroll
    for (int c = 0; c < 6; ++c) acc = fmaf(x[c], w[o*6+c], acc);
    z[o] = acc;
  }
  float q[64];
#pragma unroll
  for (int o = 0; o < 64; ++o) q[o] = z[o]*z[o];
  butterfly64(z, q, lane);
  const int ch = brev6(lane);
  red[wvi][ch]      = z[0];
  red[wvi][64 + ch] = q[0];
  __syncthreads();
  const int t = threadIdx.x;
  if (t < 128)
    part[(size_t)blockIdx.x*128 + t] = red[0][t]+red[1][t]+red[2][t]+red[3][t];
}

__device__ __forceinline__ void lean_h1(const float* __restrict__ xr,
                                        const float* __restrict__ w1,
                                        const float* __restrict__ b1,
                                        const float* __restrict__ ab1,
                                        float (&h)[64]) {
  float x[6];
#pragma unroll
  for (int c = 0; c < 6; ++c) x[c] = xr[c];
#pragma unroll
  for (int o = 0; o < 64; ++o) {
    float acc = b1[o];
#pragma unroll
    for (int c = 0; c < 6; ++c) acc = fmaf(x[c], w1[o*6+c], acc);
    h[o] = fmaxf(0.f, fmaf(acc, ab1[o], ab1[64+o]));
  }
}

__global__ __launch_bounds__(256) void stats2_store(const float* __restrict__ x0,
                                                    const float* __restrict__ w1,
                                                    const float* __restrict__ b1,
                                                    const float* __restrict__ ab1,
                                                    const float* __restrict__ w2,
                                                    const float* __restrict__ b2,
                                                    unsigned* __restrict__ z2u,
                                                    float* __restrict__ part) {
  const int r = blockIdx.x * 256 + threadIdx.x;
  const int lane = threadIdx.x & 63;
  const int wvi = threadIdx.x >> 6;
  __shared__ float red[4][128];
  float h[64];
  lean_h1(x0 + (size_t)r*6, w1, b1, ab1, h);
  float z[64];
#pragma unroll
  for (int o = 0; o < 64; ++o) {
    float acc = b2[o];
#pragma unroll
    for (int c = 0; c < 64; ++c) acc = fmaf(h[c], w2[o*64+c], acc);
    z[o] = acc;
  }
  uint4* zw = (uint4*)(z2u + (size_t)r * 32);
#pragma unroll
  for (int i = 0; i < 8; ++i)
    zw[i] = make_uint4(pack_bf2(z[8*i+0],z[8*i+1]), pack_bf2(z[8*i+2],z[8*i+3]),
                       pack_bf2(z[8*i+4],z[8*i+5]), pack_bf2(z[8*i+6],z[8*i+7]));
  float q[64];
#pragma unroll
  for (int o = 0; o < 64; ++o) q[o] = z[o]*z[o];
  butterfly64(z, q, lane);
  const int ch = brev6(lane);
  red[wvi][ch]      = z[0];
  red[wvi][64 + ch] = q[0];
  __syncthreads();
  const int t = threadIdx.x;
  if (t < 128)
    part[(size_t)blockIdx.x*128 + t] = red[0][t]+red[1][t]+red[2][t]+red[3][t];
}

__global__ __launch_bounds__(256) void stats2_plain(const float* __restrict__ x0,
                                                    const float* __restrict__ w1,
                                                    const float* __restrict__ b1,
                                                    const float* __restrict__ ab1,
                                                    const float* __restrict__ w2,
                                                    const float* __restrict__ b2,
                                                    float* __restrict__ part) {
  const int r = blockIdx.x * 256 + threadIdx.x;
  const int lane = threadIdx.x & 63;
  const int wvi = threadIdx.x >> 6;
  __shared__ float red[4][128];
  float h[64];
  lean_h1(x0 + (size_t)r*6, w1, b1, ab1, h);
  float z[64];
#pragma unroll
  for (int o = 0; o < 64; ++o) {
    float acc = b2[o];
#pragma unroll
    for (int c = 0; c < 64; ++c) acc = fmaf(h[c], w2[o*64+c], acc);
    z[o] = acc;
  }
  float q[64];
#pragma unroll
  for (int o = 0; o < 64; ++o) q[o] = z[o]*z[o];
  butterfly64(z, q, lane);
  const int ch = brev6(lane);
  red[wvi][ch]      = z[0];
  red[wvi][64 + ch] = q[0];
  __syncthreads();
  const int t = threadIdx.x;
  if (t < 128)
    part[(size_t)blockIdx.x*128 + t] = red[0][t]+red[1][t]+red[2][t]+red[3][t];
}

__global__ __launch_bounds__(256) void stats3_read(const unsigned* __restrict__ z2u,
                                                   const float* __restrict__ ab,
                                                   const float* __restrict__ w,
                                                   const float* __restrict__ bias,
                                                   unsigned* __restrict__ z3u,
                                                   float* __restrict__ part) {
  const int r = blockIdx.x * 256 + threadIdx.x;
  const int lane = threadIdx.x & 63;
  const int wvi = threadIdx.x >> 6;
  __shared__ float red[4][256];
  const uint4* zr = (const uint4*)(z2u + (size_t)r * 32);
  float h[64];
#pragma unroll
  for (int i = 0; i < 8; ++i) {
    uint4 v = zr[i];
    const int c = i*8;
    h[c+0]=fmaxf(0.f,fmaf(bf_lo(v.x),ab[c+0],ab[64+c+0]));
    h[c+1]=fmaxf(0.f,fmaf(bf_hi(v.x),ab[c+1],ab[64+c+1]));
    h[c+2]=fmaxf(0.f,fmaf(bf_lo(v.y),ab[c+2],ab[64+c+2]));
    h[c+3]=fmaxf(0.f,fmaf(bf_hi(v.y),ab[c+3],ab[64+c+3]));
    h[c+4]=fmaxf(0.f,fmaf(bf_lo(v.z),ab[c+4],ab[64+c+4]));
    h[c+5]=fmaxf(0.f,fmaf(bf_hi(v.z),ab[c+5],ab[64+c+5]));
    h[c+6]=fmaxf(0.f,fmaf(bf_lo(v.w),ab[c+6],ab[64+c+6]));
    h[c+7]=fmaxf(0.f,fmaf(bf_hi(v.w),ab[c+7],ab[64+c+7]));
  }
#pragma unroll
  for (int chunk = 0; chunk < 2; ++chunk) {
    float z[64];
#pragma unroll
    for (int o = 0; o < 64; ++o) {
      float acc = bias[chunk*64+o];
#pragma unroll
      for (int c = 0; c < 64; ++c) acc = fmaf(h[c], w[(chunk*64+o)*64+c], acc);
      z[o] = acc;
    }
    uint4* zw = (uint4*)(z3u + (size_t)r * 64 + chunk*32);
#pragma unroll
    for (int i = 0; i < 8; ++i)
      zw[i] = make_uint4(pack_bf2(z[8*i+0],z[8*i+1]), pack_bf2(z[8*i+2],z[8*i+3]),
                         pack_bf2(z[8*i+4],z[8*i+5]), pack_bf2(z[8*i+6],z[8*i+7]));
    float q[64];
#pragma unroll
    for (int o = 0; o < 64; ++o) q[o] = z[o]*z[o];
    butterfly64(z, q, lane);
    const int ch = brev6(lane);
    red[wvi][chunk*64 + ch]       = z[0];
    red[wvi][128 + chunk*64 + ch] = q[0];
  }
  __syncthreads();
  const int t = threadIdx.x;
  part[(size_t)blockIdx.x*256 + t] = red[0][t]+red[1][t]+red[2][t]+red[3][t];
}

__device__ __forceinline__ void lean_h2(const float* __restrict__ xr,
                                        const float* __restrict__ w1,
                                        const float* __restrict__ b1,
                                        const float* __restrict__ ab1,
                                        const float* __restrict__ w2,
                                        const float* __restrict__ b2,
                                        const float* __restrict__ ab2,
                                        float (&h)[64]) {
  float h1[64];
  lean_h1(xr, w1, b1, ab1, h1);
#pragma unroll
  for (int o = 0; o < 64; ++o) {
    float acc = b2[o];
#pragma unroll
    for (int c = 0; c < 64; ++c) acc = fmaf(h1[c], w2[o*64+c], acc);
    h[o] = acc;
  }
#pragma unroll
  for (int o = 0; o < 64; ++o) h[o] = fmaxf(0.f, fmaf(h[o], ab2[o], ab2[64+o]));
}

__global__ __launch_bounds__(256) void stats3_store(const float* __restrict__ x0,
                                                    const float* __restrict__ w1,
                                                    const float* __restrict__ b1,
                                                    const float* __restrict__ ab1,
                                                    const float* __restrict__ w2,
                                                    const float* __restrict__ b2,
                                                    const float* __restrict__ ab2,
                                                    const float* __restrict__ w3,
                                                    const float* __restrict__ b3,
                                                    unsigned* __restrict__ z3u,
                                                    float* __restrict__ part) {
  const int r = blockIdx.x * 256 + threadIdx.x;
  const int lane = threadIdx.x & 63;
  const int wvi = threadIdx.x >> 6;
  __shared__ float red[4][256];
  float h[64];
  lean_h2(x0 + (size_t)r*6, w1, b1, ab1, w2, b2, ab2, h);
#pragma unroll
  for (int chunk = 0; chunk < 2; ++chunk) {
    float z[64];
#pragma unroll
    for (int o = 0; o < 64; ++o) {
      float acc = b3[chunk*64+o];
#pragma unroll
      for (int c = 0; c < 64; ++c) acc = fmaf(h[c], w3[(chunk*64+o)*64+c], acc);
      z[o] = acc;
    }
    uint4* zw = (uint4*)(z3u + (size_t)r * 64 + chunk*32);
#pragma unroll
    for (int i = 0; i < 8; ++i)
      zw[i] = make_uint4(pack_bf2(z[8*i+0],z[8*i+1]), pack_bf2(z[8*i+2],z[8*i+3]),
                         pack_bf2(z[8*i+4],z[8*i+5]), pack_bf2(z[8*i+6],z[8*i+7]));
    float q[64];
#pragma unroll
    for (int o = 0; o < 64; ++o) q[o] = z[o]*z[o];
    butterfly64(z, q, lane);
    const int ch = brev6(lane);
    red[wvi][chunk*64 + ch]       = z[0];
    red[wvi][128 + chunk*64 + ch] = q[0];
  }
  __syncthreads();
  const int t = threadIdx.x;
  part[(size_t)blockIdx.x*256 + t] = red[0][t]+red[1][t]+red[2][t]+red[3][t];
}

__global__ __launch_bounds__(64) void pool_mid(const unsigned* __restrict__ z3u,
                                               const float* __restrict__ ab,
                                               float* __restrict__ outp) {
  const int g = blockIdx.x;
  const int j = threadIdx.x;
  const float sc0 = ab[2*j],   sh0 = ab[128+2*j];
  const float sc1 = ab[2*j+1], sh1 = ab[128+2*j+1];
  const unsigned* col = z3u + (size_t)g * NK * 64 + j;
  float m0 = 0.f, m1 = 0.f;
#pragma unroll 4
  for (int k = 0; k < NK; ++k) {
    unsigned u = col[(size_t)k*64];
    m0 = fmaxf(m0, fmaf(bf_lo(u), sc0, sh0));
    m1 = fmaxf(m1, fmaf(bf_hi(u), sc1, sh1));
  }
  outp[(size_t)g*128 + 2*j]   = m0;
  outp[(size_t)g*128 + 2*j+1] = m1;
}

// ============================ launcher ============================

extern "C" void kernel_launch(void* const* d_in, const int* in_sizes, int n_in,
                              void* d_out, int out_size, void* d_ws, size_t ws_size,
                              hipStream_t stream) {
  (void)in_sizes; (void)n_in; (void)out_size;
  const float* xyz = (const float*)d_in[0];
  const float* pts = (const float*)d_in[1];
  const float* w1  = (const float*)d_in[2];
  const float* b1  = (const float*)d_in[3];
  const float* g1  = (const float*)d_in[4];
  const float* be1 = (const float*)d_in[5];
  const float* w2  = (const float*)d_in[6];
  const float* b2  = (const float*)d_in[7];
  const float* g2  = (const float*)d_in[8];
  const float* be2 = (const float*)d_in[9];
  const float* w3  = (const float*)d_in[10];
  const float* b3  = (const float*)d_in[11];
  const float* g3  = (const float*)d_in[12];
  const float* be3 = (const float*)d_in[13];

  float* out = (float*)d_out;
  float* new_xyz    = out;
  float* new_points = out + NB*NS*3;

  // layout: x0 (12.6MB) | part (8MB) | ab (2KB) | z3u (134MB) [| z2u (67MB)]
  float* ws = (float*)d_ws;
  float* x0   = ws;
  float* part = x0 + (size_t)NR*6;
  float* ab   = part + 2097152;
  float* ab1  = ab;
  float* ab2  = ab + 128;
  float* ab3  = ab + 256;
  unsigned* z3u = (unsigned*)(ab + 512);
  unsigned* z2u = z3u + (size_t)NR*64;
  const size_t tierA_bytes = ((size_t)NR*6 + 2097152 + 512)*4 + (size_t)NR*64*4; // 155.2 MB
  const size_t tierB_bytes = tierA_bytes + (size_t)NR*32*4;                      // 222.3 MB
  const bool tierB = (ws_size >= tierB_bytes);
  const int NBLK = NR/256;                        // 2048 part rows

  hipLaunchKernelGGL(fps_kernel, dim3(NB), dim3(1024), 0, stream, xyz, new_xyz);
  hipLaunchKernelGGL(ballquery_kernel, dim3(NB*NS/4), dim3(256), 0, stream, xyz, pts, new_xyz, x0);

  hipLaunchKernelGGL(stats1_kernel, dim3(NBLK), dim3(256), 0, stream, x0, w1, b1, part);
  hipLaunchKernelGGL(finalize_kernel, dim3(64), dim3(256), 0, stream, part, NBLK, 128, 64, g1, be1, ab1);

  if (tierB) {
    hipLaunchKernelGGL(stats2_store, dim3(NBLK), dim3(256), 0, stream,
                       x0, w1, b1, ab1, w2, b2, z2u, part);
    hipLaunchKernelGGL(finalize_kernel, dim3(64), dim3(256), 0, stream, part, NBLK, 128, 64, g2, be2, ab2);
    hipLaunchKernelGGL(stats3_read, dim3(NBLK), dim3(256), 0, stream,
                       z2u, ab2, w3, b3, z3u, part);
  } else {
    hipLaunchKernelGGL(stats2_plain, dim3(NBLK), dim3(256), 0, stream,
                       x0, w1, b1, ab1, w2, b2, part);
    hipLaunchKernelGGL(finalize_kernel, dim3(64), dim3(256), 0, stream, part, NBLK, 128, 64, g2, be2, ab2);
    hipLaunchKernelGGL(stats3_store, dim3(NBLK), dim3(256), 0, stream,
                       x0, w1, b1, ab1, w2, b2, ab2, w3, b3, z3u, part);
  }
  hipLaunchKernelGGL(finalize_kernel, dim3(128), dim3(256), 0, stream, part, NBLK, 256, 128, g3, be3, ab3);
  hipLaunchKernelGGL(pool_mid, dim3(NB*NS), dim3(64), 0, stream, z3u, ab3, new_points);
}

// Round 14
// 1973.946 us; speedup vs baseline: 1.0948x; 1.0948x over previous
//
#include <hip/hip_runtime.h>

#define NB 16
#define NN 8192
#define NS 1024
#define NK 32
#define NR (NB*NS*NK)   // 524288 rows through the MLP

static __device__ __forceinline__ int brev6(int l) {
  return ((l&1)<<5)|((l&2)<<3)|((l&4)<<1)|((l&8)>>1)|((l&16)>>3)|((l&32)>>5);
}

// pack two f32 -> two bf16 (RNE) in one uint (low = first)
static __device__ __forceinline__ unsigned pack_bf2(float a, float b) {
  unsigned ua = __float_as_uint(a), ub = __float_as_uint(b);
  ua += 0x7fffu + ((ua >> 16) & 1u);
  ub += 0x7fffu + ((ub >> 16) & 1u);
  return (ua >> 16) | (ub & 0xffff0000u);
}
static __device__ __forceinline__ float bf_lo(unsigned u) { return __uint_as_float(u << 16); }
static __device__ __forceinline__ float bf_hi(unsigned u) { return __uint_as_float(u & 0xffff0000u); }

// ---------------------------------------------------------------------------
// FPS (r11-exact, best measured 1090 us): 512 thr (8 waves, 2/SIMD),
// 16 pts/thread, SCALAR __fmul_rn/__fadd_rn arithmetic (bit-proven; packed
// variants r10/r12 changed decisions — never again), cheap argmax
// (f32 shuffle-max + equality scan + ballot min-index, first-index
// tie-break), LDS xyz mirror, one barrier/step.
// Tile record: 256thr=1234us, 512thr=1090us, 1024thr=1274us.
// ---------------------------------------------------------------------------
__global__ __launch_bounds__(512, 1) void fps_kernel(const float* __restrict__ xyz,
                                                     float* __restrict__ new_xyz) {
  const int b = blockIdx.x;
  const int t = threadIdx.x;
  const int lane = t & 63;
  const int wv = t >> 6;
  const float* base = xyz + (size_t)b * NN * 3;

  __shared__ float sx[NN], sy[NN], sz[NN];
  __shared__ unsigned long long s_wb[2][8];

  float px[16], py[16], pz[16], dist[16];
#pragma unroll
  for (int j = 0; j < 16; ++j) {
    int p = j * 512 + t;
    float x = base[p*3+0], y = base[p*3+1], z = base[p*3+2];
    px[j] = x; py[j] = y; pz[j] = z; dist[j] = 1e10f;
    sx[p] = x; sy[p] = y; sz[p] = z;
  }
  __syncthreads();

  float cx = sx[0], cy = sy[0], cz = sz[0];
  float* outp = new_xyz + (size_t)b * NS * 3;
  if (t == 0) { outp[0] = cx; outp[1] = cy; outp[2] = cz; }

  for (int s = 1; s < NS; ++s) {
    const int par = s & 1;
    float bestv = -1.0f;
#pragma unroll
    for (int j = 0; j < 16; ++j) {
      float dx = px[j]-cx, dy = py[j]-cy, dz = pz[j]-cz;
      // exact numpy order: (dx*dx + dy*dy) + dz*dz, no contraction possible
      float d = __fadd_rn(__fadd_rn(__fmul_rn(dx,dx),__fmul_rn(dy,dy)),__fmul_rn(dz,dz));
      float nd = fminf(dist[j], d);
      dist[j] = nd;
      bestv = fmaxf(bestv, nd);
    }
    // wave max (f32 butterfly)
    float wmax = bestv;
#pragma unroll
    for (int off = 32; off >= 1; off >>= 1)
      wmax = fmaxf(wmax, __shfl_xor(wmax, off, 64));
    // smallest matching j in this lane (descending overwrite scan)
    int minj = 0;
#pragma unroll
    for (int j = 15; j >= 0; --j) if (dist[j] == wmax) minj = j;
    const int myidx = minj * 512 + t;
    // resolve min index among lanes attaining wmax
    const unsigned long long mask = __ballot(bestv == wmax);
    int l0 = __ffsll((unsigned long long)mask) - 1;
    int widx = __shfl(myidx, l0, 64);
    if (__popcll(mask) > 1) {                    // wave-uniform rare path
      unsigned long long m = mask & (mask - 1);
      while (m) {
        int l = __ffsll((unsigned long long)m) - 1;
        int v = __shfl(myidx, l, 64);
        widx = min(widx, v);
        m &= m - 1;
      }
    }
    if (lane == 0)
      s_wb[par][wv] = ((unsigned long long)__float_as_uint(wmax) << 32)
                      | (unsigned)(8191 - widx);
    __syncthreads();                             // the only barrier per step
    unsigned long long gk = s_wb[par][0];
#pragma unroll
    for (int i = 1; i < 8; ++i) {
      unsigned long long ki = s_wb[par][i]; if (ki > gk) gk = ki;
    }
    const int bi = 8191 - (int)(gk & 0xffffull);
    cx = sx[bi]; cy = sy[bi]; cz = sz[bi];
    if (t == 0) {
      float* o = outp + s*3;
      o[0] = cx; o[1] = cy; o[2] = cz;
    }
  }
}

// ---------------------------------------------------------------------------
// Ball query + gather + concat (unchanged, PASSES).
// ---------------------------------------------------------------------------
__global__ __launch_bounds__(256) void ballquery_kernel(const float* __restrict__ xyz,
                                                        const float* __restrict__ pts,
                                                        const float* __restrict__ new_xyz,
                                                        float* __restrict__ x0) {
  const int gw = ((blockIdx.x << 8) + threadIdx.x) >> 6;
  const int lane = threadIdx.x & 63;
  const int b = gw >> 10;
  const float* base = xyz + (size_t)b * NN * 3;
  const float* pbase = pts + (size_t)b * NN * 3;
  const float* cp = new_xyz + (size_t)gw * 3;
  const float cx = cp[0], cy = cp[1], cz = cp[2];
  const float t1 = __fadd_rn(__fadd_rn(__fmul_rn(cx,cx),__fmul_rn(cy,cy)),__fmul_rn(cz,cz));
  const float R2 = 0.04f;
  float* out = x0 + (size_t)gw * (NK*6);

  int count = 0, pfirst = 0;
  for (int n0 = 0; n0 < NN; n0 += 64) {
    const int p = n0 + lane;
    const float ax = base[p*3], ay = base[p*3+1], az = base[p*3+2];
    const float t2 = __fadd_rn(__fadd_rn(__fmul_rn(ax,ax),__fmul_rn(ay,ay)),__fmul_rn(az,az));
    const float dt = __fmaf_rn(cz, az, __fmaf_rn(cy, ay, __fmul_rn(cx, ax)));
    const float sq = __fadd_rn(__fsub_rn(t1, __fmul_rn(2.0f,dt)), t2);
    const bool keep = !(sq > R2);
    const unsigned long long mask = __ballot(keep);
    const int slot = count + __popcll(mask & ((1ull<<lane)-1ull));
    if (keep && slot < NK) {
      float* o = out + slot*6;
      o[0]=ax-cx; o[1]=ay-cy; o[2]=az-cz;
      o[3]=pbase[p*3]; o[4]=pbase[p*3+1]; o[5]=pbase[p*3+2];
    }
    if (count == 0 && mask != 0ull) pfirst = n0 + (__ffsll((unsigned long long)mask) - 1);
    count += __popcll(mask);
    if (count >= NK) break;
  }
  if (count < NK) {
    const float* fx = base + (size_t)pfirst*3;
    const float* fp = pbase + (size_t)pfirst*3;
    const float a0 = fx[0]-cx, a1 = fx[1]-cy, a2 = fx[2]-cz;
    const float a3 = fp[0], a4 = fp[1], a5 = fp[2];
    for (int sl = count + lane; sl < NK; sl += 64) {
      float* o = out + sl*6;
      o[0]=a0;o[1]=a1;o[2]=a2;o[3]=a3;o[4]=a4;o[5]=a5;
    }
  }
}

// ---------------------------------------------------------------------------
// butterfly64: z[0] = wave sum of channel brev6(lane).
// ---------------------------------------------------------------------------
__device__ __forceinline__ void butterfly64(float (&z)[64], float (&q)[64], int lane) {
#pragma unroll
  for (int d = 0; d < 6; ++d) {
    const int m = 32 >> d;
    const bool hi = (lane >> d) & 1;
#pragma unroll
    for (int i = 0; i < m; ++i) {
      float sv = hi ? z[i] : z[i+m];
      float rv = __shfl_xor(sv, 1<<d, 64);
      z[i] = (hi ? z[i+m] : z[i]) + rv;
      float sq = hi ? q[i] : q[i+m];
      float rq = __shfl_xor(sq, 1<<d, 64);
      q[i] = (hi ? q[i+m] : q[i]) + rq;
    }
  }
}

// ---------------------------------------------------------------------------
// BN finalize (nrows = block count).
// ---------------------------------------------------------------------------
__global__ __launch_bounds__(256) void finalize_kernel(const float* __restrict__ part,
                                                       int nrows, int rowstride, int C,
                                                       const float* __restrict__ g,
                                                       const float* __restrict__ be,
                                                       float* __restrict__ ab) {
  const int ch = blockIdx.x;
  const int t = threadIdx.x;
  const int qo = rowstride >> 1;
  double s = 0.0, q = 0.0;
  for (int wv = t; wv < nrows; wv += 256) {
    s += (double)part[(size_t)wv*rowstride + ch];
    q += (double)part[(size_t)wv*rowstride + qo + ch];
  }
#pragma unroll
  for (int off = 32; off >= 1; off >>= 1) {
    s += __shfl_down(s, off, 64);
    q += __shfl_down(q, off, 64);
  }
  __shared__ double ls[4], lq[4];
  if ((t & 63) == 0) { ls[t>>6] = s; lq[t>>6] = q; }
  __syncthreads();
  if (t == 0) {
    double S = ls[0]+ls[1]+ls[2]+ls[3];
    double Q = lq[0]+lq[1]+lq[2]+lq[3];
    double mean = S / (double)NR;
    double var  = Q / (double)NR - mean*mean;
    double inv  = 1.0 / sqrt(var + 1e-5);
    double gg   = (double)g[ch];
    ab[ch]     = (float)(gg * inv);
    ab[C + ch] = (float)((double)be[ch] - mean * gg * inv);
  }
}

// ============================ MLP passes ============================
// Each block (4 waves) LDS-reduces its 4 wave-partials -> ONE part row per
// block (coalesced write); finalize's strided read shrinks 4x. (validated r13)

__global__ __launch_bounds__(256) void stats1_kernel(const float* __restrict__ x0,
                                                     const float* __restrict__ w,
                                                     const float* __restrict__ bias,
                                                     float* __restrict__ part) {
  const int r = blockIdx.x * 256 + threadIdx.x;
  const int lane = threadIdx.x & 63;
  const int wvi = threadIdx.x >> 6;
  __shared__ float red[4][128];
  const float* xr = x0 + (size_t)r * 6;
  float x[6];
#pragma unroll
  for (int c = 0; c < 6; ++c) x[c] = xr[c];
  float z[64];
#pragma unroll
  for (int o = 0; o < 64; ++o) {
    float acc = bias[o];
#pragma unroll
    for (int c = 0; c < 6; ++c) acc = fmaf(x[c], w[o*6+c], acc);
    z[o] = acc;
  }
  float q[64];
#pragma unroll
  for (int o = 0; o < 64; ++o) q[o] = z[o]*z[o];
  butterfly64(z, q, lane);
  const int ch = brev6(lane);
  red[wvi][ch]      = z[0];
  red[wvi][64 + ch] = q[0];
  __syncthreads();
  const int t = threadIdx.x;
  if (t < 128)
    part[(size_t)blockIdx.x*128 + t] = red[0][t]+red[1][t]+red[2][t]+red[3][t];
}

__device__ __forceinline__ void lean_h1(const float* __restrict__ xr,
                                        const float* __restrict__ w1,
                                        const float* __restrict__ b1,
                                        const float* __restrict__ ab1,
                                        float (&h)[64]) {
  float x[6];
#pragma unroll
  for (int c = 0; c < 6; ++c) x[c] = xr[c];
#pragma unroll
  for (int o = 0; o < 64; ++o) {
    float acc = b1[o];
#pragma unroll
    for (int c = 0; c < 6; ++c) acc = fmaf(x[c], w1[o*6+c], acc);
    h[o] = fmaxf(0.f, fmaf(acc, ab1[o], ab1[64+o]));
  }
}

__global__ __launch_bounds__(256) void stats2_store(const float* __restrict__ x0,
                                                    const float* __restrict__ w1,
                                                    const float* __restrict__ b1,
                                                    const float* __restrict__ ab1,
                                                    const float* __restrict__ w2,
                                                    const float* __restrict__ b2,
                                                    unsigned* __restrict__ z2u,
                                                    float* __restrict__ part) {
  const int r = blockIdx.x * 256 + threadIdx.x;
  const int lane = threadIdx.x & 63;
  const int wvi = threadIdx.x >> 6;
  __shared__ float red[4][128];
  float h[64];
  lean_h1(x0 + (size_t)r*6, w1, b1, ab1, h);
  float z[64];
#pragma unroll
  for (int o = 0; o < 64; ++o) {
    float acc = b2[o];
#pragma unroll
    for (int c = 0; c < 64; ++c) acc = fmaf(h[c], w2[o*64+c], acc);
    z[o] = acc;
  }
  uint4* zw = (uint4*)(z2u + (size_t)r * 32);
#pragma unroll
  for (int i = 0; i < 8; ++i)
    zw[i] = make_uint4(pack_bf2(z[8*i+0],z[8*i+1]), pack_bf2(z[8*i+2],z[8*i+3]),
                       pack_bf2(z[8*i+4],z[8*i+5]), pack_bf2(z[8*i+6],z[8*i+7]));
  float q[64];
#pragma unroll
  for (int o = 0; o < 64; ++o) q[o] = z[o]*z[o];
  butterfly64(z, q, lane);
  const int ch = brev6(lane);
  red[wvi][ch]      = z[0];
  red[wvi][64 + ch] = q[0];
  __syncthreads();
  const int t = threadIdx.x;
  if (t < 128)
    part[(size_t)blockIdx.x*128 + t] = red[0][t]+red[1][t]+red[2][t]+red[3][t];
}

__global__ __launch_bounds__(256) void stats2_plain(const float* __restrict__ x0,
                                                    const float* __restrict__ w1,
                                                    const float* __restrict__ b1,
                                                    const float* __restrict__ ab1,
                                                    const float* __restrict__ w2,
                                                    const float* __restrict__ b2,
                                                    float* __restrict__ part) {
  const int r = blockIdx.x * 256 + threadIdx.x;
  const int lane = threadIdx.x & 63;
  const int wvi = threadIdx.x >> 6;
  __shared__ float red[4][128];
  float h[64];
  lean_h1(x0 + (size_t)r*6, w1, b1, ab1, h);
  float z[64];
#pragma unroll
  for (int o = 0; o < 64; ++o) {
    float acc = b2[o];
#pragma unroll
    for (int c = 0; c < 64; ++c) acc = fmaf(h[c], w2[o*64+c], acc);
    z[o] = acc;
  }
  float q[64];
#pragma unroll
  for (int o = 0; o < 64; ++o) q[o] = z[o]*z[o];
  butterfly64(z, q, lane);
  const int ch = brev6(lane);
  red[wvi][ch]      = z[0];
  red[wvi][64 + ch] = q[0];
  __syncthreads();
  const int t = threadIdx.x;
  if (t < 128)
    part[(size_t)blockIdx.x*128 + t] = red[0][t]+red[1][t]+red[2][t]+red[3][t];
}

__global__ __launch_bounds__(256) void stats3_read(const unsigned* __restrict__ z2u,
                                                   const float* __restrict__ ab,
                                                   const float* __restrict__ w,
                                                   const float* __restrict__ bias,
                                                   unsigned* __restrict__ z3u,
                                                   float* __restrict__ part) {
  const int r = blockIdx.x * 256 + threadIdx.x;
  const int lane = threadIdx.x & 63;
  const int wvi = threadIdx.x >> 6;
  __shared__ float red[4][256];
  const uint4* zr = (const uint4*)(z2u + (size_t)r * 32);
  float h[64];
#pragma unroll
  for (int i = 0; i < 8; ++i) {
    uint4 v = zr[i];
    const int c = i*8;
    h[c+0]=fmaxf(0.f,fmaf(bf_lo(v.x),ab[c+0],ab[64+c+0]));
    h[c+1]=fmaxf(0.f,fmaf(bf_hi(v.x),ab[c+1],ab[64+c+1]));
    h[c+2]=fmaxf(0.f,fmaf(bf_lo(v.y),ab[c+2],ab[64+c+2]));
    h[c+3]=fmaxf(0.f,fmaf(bf_hi(v.y),ab[c+3],ab[64+c+3]));
    h[c+4]=fmaxf(0.f,fmaf(bf_lo(v.z),ab[c+4],ab[64+c+4]));
    h[c+5]=fmaxf(0.f,fmaf(bf_hi(v.z),ab[c+5],ab[64+c+5]));
    h[c+6]=fmaxf(0.f,fmaf(bf_lo(v.w),ab[c+6],ab[64+c+6]));
    h[c+7]=fmaxf(0.f,fmaf(bf_hi(v.w),ab[c+7],ab[64+c+7]));
  }
#pragma unroll
  for (int chunk = 0; chunk < 2; ++chunk) {
    float z[64];
#pragma unroll
    for (int o = 0; o < 64; ++o) {
      float acc = bias[chunk*64+o];
#pragma unroll
      for (int c = 0; c < 64; ++c) acc = fmaf(h[c], w[(chunk*64+o)*64+c], acc);
      z[o] = acc;
    }
    uint4* zw = (uint4*)(z3u + (size_t)r * 64 + chunk*32);
#pragma unroll
    for (int i = 0; i < 8; ++i)
      zw[i] = make_uint4(pack_bf2(z[8*i+0],z[8*i+1]), pack_bf2(z[8*i+2],z[8*i+3]),
                         pack_bf2(z[8*i+4],z[8*i+5]), pack_bf2(z[8*i+6],z[8*i+7]));
    float q[64];
#pragma unroll
    for (int o = 0; o < 64; ++o) q[o] = z[o]*z[o];
    butterfly64(z, q, lane);
    const int ch = brev6(lane);
    red[wvi][chunk*64 + ch]       = z[0];
    red[wvi][128 + chunk*64 + ch] = q[0];
  }
  __syncthreads();
  const int t = threadIdx.x;
  part[(size_t)blockIdx.x*256 + t] = red[0][t]+red[1][t]+red[2][t]+red[3][t];
}

__device__ __forceinline__ void lean_h2(const float* __restrict__ xr,
                                        const float* __restrict__ w1,
                                        const float* __restrict__ b1,
                                        const float* __restrict__ ab1,
                                        const float* __restrict__ w2,
                                        const float* __restrict__ b2,
                                        const float* __restrict__ ab2,
                                        float (&h)[64]) {
  float h1[64];
  lean_h1(xr, w1, b1, ab1, h1);
#pragma unroll
  for (int o = 0; o < 64; ++o) {
    float acc = b2[o];
#pragma unroll
    for (int c = 0; c < 64; ++c) acc = fmaf(h1[c], w2[o*64+c], acc);
    h[o] = acc;
  }
#pragma unroll
  for (int o = 0; o < 64; ++o) h[o] = fmaxf(0.f, fmaf(h[o], ab2[o], ab2[64+o]));
}

__global__ __launch_bounds__(256) void stats3_store(const float* __restrict__ x0,
                                                    const float* __restrict__ w1,
                                                    const float* __restrict__ b1,
                                                    const float* __restrict__ ab1,
                                                    const float* __restrict__ w2,
                                                    const float* __restrict__ b2,
                                                    const float* __restrict__ ab2,
                                                    const float* __restrict__ w3,
                                                    const float* __restrict__ b3,
                                                    unsigned* __restrict__ z3u,
                                                    float* __restrict__ part) {
  const int r = blockIdx.x * 256 + threadIdx.x;
  const int lane = threadIdx.x & 63;
  const int wvi = threadIdx.x >> 6;
  __shared__ float red[4][256];
  float h[64];
  lean_h2(x0 + (size_t)r*6, w1, b1, ab1, w2, b2, ab2, h);
#pragma unroll
  for (int chunk = 0; chunk < 2; ++chunk) {
    float z[64];
#pragma unroll
    for (int o = 0; o < 64; ++o) {
      float acc = b3[chunk*64+o];
#pragma unroll
      for (int c = 0; c < 64; ++c) acc = fmaf(h[c], w3[(chunk*64+o)*64+c], acc);
      z[o] = acc;
    }
    uint4* zw = (uint4*)(z3u + (size_t)r * 64 + chunk*32);
#pragma unroll
    for (int i = 0; i < 8; ++i)
      zw[i] = make_uint4(pack_bf2(z[8*i+0],z[8*i+1]), pack_bf2(z[8*i+2],z[8*i+3]),
                         pack_bf2(z[8*i+4],z[8*i+5]), pack_bf2(z[8*i+6],z[8*i+7]));
    float q[64];
#pragma unroll
    for (int o = 0; o < 64; ++o) q[o] = z[o]*z[o];
    butterfly64(z, q, lane);
    const int ch = brev6(lane);
    red[wvi][chunk*64 + ch]       = z[0];
    red[wvi][128 + chunk*64 + ch] = q[0];
  }
  __syncthreads();
  const int t = threadIdx.x;
  part[(size_t)blockIdx.x*256 + t] = red[0][t]+red[1][t]+red[2][t]+red[3][t];
}

__global__ __launch_bounds__(64) void pool_mid(const unsigned* __restrict__ z3u,
                                               const float* __restrict__ ab,
                                               float* __restrict__ outp) {
  const int g = blockIdx.x;
  const int j = threadIdx.x;
  const float sc0 = ab[2*j],   sh0 = ab[128+2*j];
  const float sc1 = ab[2*j+1], sh1 = ab[128+2*j+1];
  const unsigned* col = z3u + (size_t)g * NK * 64 + j;
  float m0 = 0.f, m1 = 0.f;
#pragma unroll 4
  for (int k = 0; k < NK; ++k) {
    unsigned u = col[(size_t)k*64];
    m0 = fmaxf(m0, fmaf(bf_lo(u), sc0, sh0));
    m1 = fmaxf(m1, fmaf(bf_hi(u), sc1, sh1));
  }
  outp[(size_t)g*128 + 2*j]   = m0;
  outp[(size_t)g*128 + 2*j+1] = m1;
}

// ============================ launcher ============================

extern "C" void kernel_launch(void* const* d_in, const int* in_sizes, int n_in,
                              void* d_out, int out_size, void* d_ws, size_t ws_size,
                              hipStream_t stream) {
  (void)in_sizes; (void)n_in; (void)out_size;
  const float* xyz = (const float*)d_in[0];
  const float* pts = (const float*)d_in[1];
  const float* w1  = (const float*)d_in[2];
  const float* b1  = (const float*)d_in[3];
  const float* g1  = (const float*)d_in[4];
  const float* be1 = (const float*)d_in[5];
  const float* w2  = (const float*)d_in[6];
  const float* b2  = (const float*)d_in[7];
  const float* g2  = (const float*)d_in[8];
  const float* be2 = (const float*)d_in[9];
  const float* w3  = (const float*)d_in[10];
  const float* b3  = (const float*)d_in[11];
  const float* g3  = (const float*)d_in[12];
  const float* be3 = (const float*)d_in[13];

  float* out = (float*)d_out;
  float* new_xyz    = out;
  float* new_points = out + NB*NS*3;

  // layout: x0 (12.6MB) | part (8MB) | ab (2KB) | z3u (134MB) [| z2u (67MB)]
  float* ws = (float*)d_ws;
  float* x0   = ws;
  float* part = x0 + (size_t)NR*6;
  float* ab   = part + 2097152;
  float* ab1  = ab;
  float* ab2  = ab + 128;
  float* ab3  = ab + 256;
  unsigned* z3u = (unsigned*)(ab + 512);
  unsigned* z2u = z3u + (size_t)NR*64;
  const size_t tierA_bytes = ((size_t)NR*6 + 2097152 + 512)*4 + (size_t)NR*64*4; // 155.2 MB
  const size_t tierB_bytes = tierA_bytes + (size_t)NR*32*4;                      // 222.3 MB
  const bool tierB = (ws_size >= tierB_bytes);
  const int NBLK = NR/256;                        // 2048 part rows

  hipLaunchKernelGGL(fps_kernel, dim3(NB), dim3(512), 0, stream, xyz, new_xyz);
  hipLaunchKernelGGL(ballquery_kernel, dim3(NB*NS/4), dim3(256), 0, stream, xyz, pts, new_xyz, x0);

  hipLaunchKernelGGL(stats1_kernel, dim3(NBLK), dim3(256), 0, stream, x0, w1, b1, part);
  hipLaunchKernelGGL(finalize_kernel, dim3(64), dim3(256), 0, stream, part, NBLK, 128, 64, g1, be1, ab1);

  if (tierB) {
    hipLaunchKernelGGL(stats2_store, dim3(NBLK), dim3(256), 0, stream,
                       x0, w1, b1, ab1, w2, b2, z2u, part);
    hipLaunchKernelGGL(finalize_kernel, dim3(64), dim3(256), 0, stream, part, NBLK, 128, 64, g2, be2, ab2);
    hipLaunchKernelGGL(stats3_read, dim3(NBLK), dim3(256), 0, stream,
                       z2u, ab2, w3, b3, z3u, part);
  } else {
    hipLaunchKernelGGL(stats2_plain, dim3(NBLK), dim3(256), 0, stream,
                       x0, w1, b1, ab1, w2, b2, part);
    hipLaunchKernelGGL(finalize_kernel, dim3(64), dim3(256), 0, stream, part, NBLK, 128, 64, g2, be2, ab2);
    hipLaunchKernelGGL(stats3_store, dim3(NBLK), dim3(256), 0, stream,
                       x0, w1, b1, ab1, w2, b2, ab2, w3, b3, z3u, part);
  }
  hipLaunchKernelGGL(finalize_kernel, dim3(128), dim3(256), 0, stream, part, NBLK, 256, 128, g3, be3, ab3);
  hipLaunchKernelGGL(pool_mid, dim3(NB*NS), dim3(64), 0, stream, z3u, ab3, new_points);
}

// Round 15
// 1774.666 us; speedup vs baseline: 1.2177x; 1.1123x over previous
//
#include <hip/hip_runtime.h>

#define NB 16
#define NN 8192
#define NS 1024
#define NK 32
#define NR (NB*NS*NK)   // 524288 rows through the MLP

static __device__ __forceinline__ int brev6(int l) {
  return ((l&1)<<5)|((l&2)<<3)|((l&4)<<1)|((l&8)>>1)|((l&16)>>3)|((l&32)>>5);
}

// pack two f32 -> two bf16 (RNE) in one uint (low = first)
static __device__ __forceinline__ unsigned pack_bf2(float a, float b) {
  unsigned ua = __float_as_uint(a), ub = __float_as_uint(b);
  ua += 0x7fffu + ((ua >> 16) & 1u);
  ub += 0x7fffu + ((ub >> 16) & 1u);
  return (ua >> 16) | (ub & 0xffff0000u);
}
static __device__ __forceinline__ float bf_lo(unsigned u) { return __uint_as_float(u << 16); }
static __device__ __forceinline__ float bf_hi(unsigned u) { return __uint_as_float(u & 0xffff0000u); }

// ---------------------------------------------------------------------------
// FPS (r11-exact, best measured 1090 us): 512 thr, 16 pts/thread, SCALAR
// __fmul_rn/__fadd_rn arithmetic (bit-proven; packed variants r10/r12 changed
// decisions — never again), cheap argmax, LDS xyz mirror, one barrier/step.
// Tile record: 256thr=1234us, 512thr=1090us, 1024thr=1274us. DO NOT TOUCH.
// ---------------------------------------------------------------------------
__global__ __launch_bounds__(512, 1) void fps_kernel(const float* __restrict__ xyz,
                                                     float* __restrict__ new_xyz) {
  const int b = blockIdx.x;
  const int t = threadIdx.x;
  const int lane = t & 63;
  const int wv = t >> 6;
  const float* base = xyz + (size_t)b * NN * 3;

  __shared__ float sx[NN], sy[NN], sz[NN];
  __shared__ unsigned long long s_wb[2][8];

  float px[16], py[16], pz[16], dist[16];
#pragma unroll
  for (int j = 0; j < 16; ++j) {
    int p = j * 512 + t;
    float x = base[p*3+0], y = base[p*3+1], z = base[p*3+2];
    px[j] = x; py[j] = y; pz[j] = z; dist[j] = 1e10f;
    sx[p] = x; sy[p] = y; sz[p] = z;
  }
  __syncthreads();

  float cx = sx[0], cy = sy[0], cz = sz[0];
  float* outp = new_xyz + (size_t)b * NS * 3;
  if (t == 0) { outp[0] = cx; outp[1] = cy; outp[2] = cz; }

  for (int s = 1; s < NS; ++s) {
    const int par = s & 1;
    float bestv = -1.0f;
#pragma unroll
    for (int j = 0; j < 16; ++j) {
      float dx = px[j]-cx, dy = py[j]-cy, dz = pz[j]-cz;
      float d = __fadd_rn(__fadd_rn(__fmul_rn(dx,dx),__fmul_rn(dy,dy)),__fmul_rn(dz,dz));
      float nd = fminf(dist[j], d);
      dist[j] = nd;
      bestv = fmaxf(bestv, nd);
    }
    float wmax = bestv;
#pragma unroll
    for (int off = 32; off >= 1; off >>= 1)
      wmax = fmaxf(wmax, __shfl_xor(wmax, off, 64));
    int minj = 0;
#pragma unroll
    for (int j = 15; j >= 0; --j) if (dist[j] == wmax) minj = j;
    const int myidx = minj * 512 + t;
    const unsigned long long mask = __ballot(bestv == wmax);
    int l0 = __ffsll((unsigned long long)mask) - 1;
    int widx = __shfl(myidx, l0, 64);
    if (__popcll(mask) > 1) {
      unsigned long long m = mask & (mask - 1);
      while (m) {
        int l = __ffsll((unsigned long long)m) - 1;
        int v = __shfl(myidx, l, 64);
        widx = min(widx, v);
        m &= m - 1;
      }
    }
    if (lane == 0)
      s_wb[par][wv] = ((unsigned long long)__float_as_uint(wmax) << 32)
                      | (unsigned)(8191 - widx);
    __syncthreads();
    unsigned long long gk = s_wb[par][0];
#pragma unroll
    for (int i = 1; i < 8; ++i) {
      unsigned long long ki = s_wb[par][i]; if (ki > gk) gk = ki;
    }
    const int bi = 8191 - (int)(gk & 0xffffull);
    cx = sx[bi]; cy = sy[bi]; cz = sz[bi];
    if (t == 0) {
      float* o = outp + s*3;
      o[0] = cx; o[1] = cy; o[2] = cz;
    }
  }
}

// ---------------------------------------------------------------------------
// Ball query + gather + concat (unchanged, PASSES).
// ---------------------------------------------------------------------------
__global__ __launch_bounds__(256) void ballquery_kernel(const float* __restrict__ xyz,
                                                        const float* __restrict__ pts,
                                                        const float* __restrict__ new_xyz,
                                                        float* __restrict__ x0) {
  const int gw = ((blockIdx.x << 8) + threadIdx.x) >> 6;
  const int lane = threadIdx.x & 63;
  const int b = gw >> 10;
  const float* base = xyz + (size_t)b * NN * 3;
  const float* pbase = pts + (size_t)b * NN * 3;
  const float* cp = new_xyz + (size_t)gw * 3;
  const float cx = cp[0], cy = cp[1], cz = cp[2];
  const float t1 = __fadd_rn(__fadd_rn(__fmul_rn(cx,cx),__fmul_rn(cy,cy)),__fmul_rn(cz,cz));
  const float R2 = 0.04f;
  float* out = x0 + (size_t)gw * (NK*6);

  int count = 0, pfirst = 0;
  for (int n0 = 0; n0 < NN; n0 += 64) {
    const int p = n0 + lane;
    const float ax = base[p*3], ay = base[p*3+1], az = base[p*3+2];
    const float t2 = __fadd_rn(__fadd_rn(__fmul_rn(ax,ax),__fmul_rn(ay,ay)),__fmul_rn(az,az));
    const float dt = __fmaf_rn(cz, az, __fmaf_rn(cy, ay, __fmul_rn(cx, ax)));
    const float sq = __fadd_rn(__fsub_rn(t1, __fmul_rn(2.0f,dt)), t2);
    const bool keep = !(sq > R2);
    const unsigned long long mask = __ballot(keep);
    const int slot = count + __popcll(mask & ((1ull<<lane)-1ull));
    if (keep && slot < NK) {
      float* o = out + slot*6;
      o[0]=ax-cx; o[1]=ay-cy; o[2]=az-cz;
      o[3]=pbase[p*3]; o[4]=pbase[p*3+1]; o[5]=pbase[p*3+2];
    }
    if (count == 0 && mask != 0ull) pfirst = n0 + (__ffsll((unsigned long long)mask) - 1);
    count += __popcll(mask);
    if (count >= NK) break;
  }
  if (count < NK) {
    const float* fx = base + (size_t)pfirst*3;
    const float* fp = pbase + (size_t)pfirst*3;
    const float a0 = fx[0]-cx, a1 = fx[1]-cy, a2 = fx[2]-cz;
    const float a3 = fp[0], a4 = fp[1], a5 = fp[2];
    for (int sl = count + lane; sl < NK; sl += 64) {
      float* o = out + sl*6;
      o[0]=a0;o[1]=a1;o[2]=a2;o[3]=a3;o[4]=a4;o[5]=a5;
    }
  }
}

// ---------------------------------------------------------------------------
// butterfly64: z[0] = wave sum of channel brev6(lane).
// ---------------------------------------------------------------------------
__device__ __forceinline__ void butterfly64(float (&z)[64], float (&q)[64], int lane) {
#pragma unroll
  for (int d = 0; d < 6; ++d) {
    const int m = 32 >> d;
    const bool hi = (lane >> d) & 1;
#pragma unroll
    for (int i = 0; i < m; ++i) {
      float sv = hi ? z[i] : z[i+m];
      float rv = __shfl_xor(sv, 1<<d, 64);
      z[i] = (hi ? z[i+m] : z[i]) + rv;
      float sq = hi ? q[i] : q[i+m];
      float rq = __shfl_xor(sq, 1<<d, 64);
      q[i] = (hi ? q[i+m] : q[i]) + rq;
    }
  }
}

// ---------------------------------------------------------------------------
// BN finalize (nrows = block count).
// ---------------------------------------------------------------------------
__global__ __launch_bounds__(256) void finalize_kernel(const float* __restrict__ part,
                                                       int nrows, int rowstride, int C,
                                                       const float* __restrict__ g,
                                                       const float* __restrict__ be,
                                                       float* __restrict__ ab) {
  const int ch = blockIdx.x;
  const int t = threadIdx.x;
  const int qo = rowstride >> 1;
  double s = 0.0, q = 0.0;
  for (int wv = t; wv < nrows; wv += 256) {
    s += (double)part[(size_t)wv*rowstride + ch];
    q += (double)part[(size_t)wv*rowstride + qo + ch];
  }
#pragma unroll
  for (int off = 32; off >= 1; off >>= 1) {
    s += __shfl_down(s, off, 64);
    q += __shfl_down(q, off, 64);
  }
  __shared__ double ls[4], lq[4];
  if ((t & 63) == 0) { ls[t>>6] = s; lq[t>>6] = q; }
  __syncthreads();
  if (t == 0) {
    double S = ls[0]+ls[1]+ls[2]+ls[3];
    double Q = lq[0]+lq[1]+lq[2]+lq[3];
    double mean = S / (double)NR;
    double var  = Q / (double)NR - mean*mean;
    double inv  = 1.0 / sqrt(var + 1e-5);
    double gg   = (double)g[ch];
    ab[ch]     = (float)(gg * inv);
    ab[C + ch] = (float)((double)be[ch] - mean * gg * inv);
  }
}

// ============================ MLP passes ============================

__global__ __launch_bounds__(256) void stats1_kernel(const float* __restrict__ x0,
                                                     const float* __restrict__ w,
                                                     const float* __restrict__ bias,
                                                     float* __restrict__ part) {
  const int r = blockIdx.x * 256 + threadIdx.x;
  const int lane = threadIdx.x & 63;
  const int wvi = threadIdx.x >> 6;
  __shared__ float red[4][128];
  const float* xr = x0 + (size_t)r * 6;
  float x[6];
#pragma unroll
  for (int c = 0; c < 6; ++c) x[c] = xr[c];
  float z[64];
#pragma unroll
  for (int o = 0; o < 64; ++o) {
    float acc = bias[o];
#pragma unroll
    for (int c = 0; c < 6; ++c) acc = fmaf(x[c], w[o*6+c], acc);
    z[o] = acc;
  }
  float q[64];
#pragma unroll
  for (int o = 0; o < 64; ++o) q[o] = z[o]*z[o];
  butterfly64(z, q, lane);
  const int ch = brev6(lane);
  red[wvi][ch]      = z[0];
  red[wvi][64 + ch] = q[0];
  __syncthreads();
  const int t = threadIdx.x;
  if (t < 128)
    part[(size_t)blockIdx.x*128 + t] = red[0][t]+red[1][t]+red[2][t]+red[3][t];
}

__device__ __forceinline__ void lean_h1(const float* __restrict__ xr,
                                        const float* __restrict__ w1,
                                        const float* __restrict__ b1,
                                        const float* __restrict__ ab1,
                                        float (&h)[64]) {
  float x[6];
#pragma unroll
  for (int c = 0; c < 6; ++c) x[c] = xr[c];
#pragma unroll
  for (int o = 0; o < 64; ++o) {
    float acc = b1[o];
#pragma unroll
    for (int c = 0; c < 6; ++c) acc = fmaf(x[c], w1[o*6+c], acc);
    h[o] = fmaxf(0.f, fmaf(acc, ab1[o], ab1[64+o]));
  }
}

__global__ __launch_bounds__(256) void stats2_store(const float* __restrict__ x0,
                                                    const float* __restrict__ w1,
                                                    const float* __restrict__ b1,
                                                    const float* __restrict__ ab1,
                                                    const float* __restrict__ w2,
                                                    const float* __restrict__ b2,
                                                    unsigned* __restrict__ z2u,
                                                    float* __restrict__ part) {
  const int r = blockIdx.x * 256 + threadIdx.x;
  const int lane = threadIdx.x & 63;
  const int wvi = threadIdx.x >> 6;
  __shared__ float red[4][128];
  float h[64];
  lean_h1(x0 + (size_t)r*6, w1, b1, ab1, h);
  float z[64];
#pragma unroll
  for (int o = 0; o < 64; ++o) {
    float acc = b2[o];
#pragma unroll
    for (int c = 0; c < 64; ++c) acc = fmaf(h[c], w2[o*64+c], acc);
    z[o] = acc;
  }
  uint4* zw = (uint4*)(z2u + (size_t)r * 32);
#pragma unroll
  for (int i = 0; i < 8; ++i)
    zw[i] = make_uint4(pack_bf2(z[8*i+0],z[8*i+1]), pack_bf2(z[8*i+2],z[8*i+3]),
                       pack_bf2(z[8*i+4],z[8*i+5]), pack_bf2(z[8*i+6],z[8*i+7]));
  float q[64];
#pragma unroll
  for (int o = 0; o < 64; ++o) q[o] = z[o]*z[o];
  butterfly64(z, q, lane);
  const int ch = brev6(lane);
  red[wvi][ch]      = z[0];
  red[wvi][64 + ch] = q[0];
  __syncthreads();
  const int t = threadIdx.x;
  if (t < 128)
    part[(size_t)blockIdx.x*128 + t] = red[0][t]+red[1][t]+red[2][t]+red[3][t];
}

// ---------------------------------------------------------------------------
// stats3_fused: read z2 bf16, bn2+relu, layer3 (2 chunks of 64 ch) -> LDS
// tile (stride 65: conflict-free row writes AND column reads) -> per-group
// (32 rows) max/min/sum/sumsq in one pass. z3 NEVER materialized; pool gone.
// kmax/kmin trick validated r7 (passed); tile layout avoids r7's shuffle
// storm and r8's split-K spill (only h[64] lives across barriers).
// ---------------------------------------------------------------------------
__global__ __launch_bounds__(256) void stats3_fused(const unsigned* __restrict__ z2u,
                                                    const float* __restrict__ ab,
                                                    const float* __restrict__ w,
                                                    const float* __restrict__ bias,
                                                    float* __restrict__ part,
                                                    float* __restrict__ kmx,
                                                    float* __restrict__ kmn) {
  const int r = blockIdx.x * 256 + threadIdx.x;
  const int t = threadIdx.x;
  const int lane = t & 63;
  const int wvi = t >> 6;                 // 0..3

  __shared__ float tile[256*65];          // 66,560 B
  __shared__ float gs[8][64], gq[8][64];  // per-group partial sum/sumsq

  const uint4* zr = (const uint4*)(z2u + (size_t)r * 32);
  float h[64];
#pragma unroll
  for (int i = 0; i < 8; ++i) {
    uint4 v = zr[i];
    const int c = i*8;
    h[c+0]=fmaxf(0.f,fmaf(bf_lo(v.x),ab[c+0],ab[64+c+0]));
    h[c+1]=fmaxf(0.f,fmaf(bf_hi(v.x),ab[c+1],ab[64+c+1]));
    h[c+2]=fmaxf(0.f,fmaf(bf_lo(v.y),ab[c+2],ab[64+c+2]));
    h[c+3]=fmaxf(0.f,fmaf(bf_hi(v.y),ab[c+3],ab[64+c+3]));
    h[c+4]=fmaxf(0.f,fmaf(bf_lo(v.z),ab[c+4],ab[64+c+4]));
    h[c+5]=fmaxf(0.f,fmaf(bf_hi(v.z),ab[c+5],ab[64+c+5]));
    h[c+6]=fmaxf(0.f,fmaf(bf_lo(v.w),ab[c+6],ab[64+c+6]));
    h[c+7]=fmaxf(0.f,fmaf(bf_hi(v.w),ab[c+7],ab[64+c+7]));
  }

#pragma unroll 1
  for (int chunk = 0; chunk < 2; ++chunk) {
    // layer3 outputs for this thread's row, 64 channels
    {
      float z[64];
#pragma unroll
      for (int o = 0; o < 64; ++o) {
        float acc = bias[chunk*64+o];
        const float* wr = w + (size_t)(chunk*64+o) * 64;
#pragma unroll
        for (int c = 0; c < 64; ++c) acc = fmaf(h[c], wr[c], acc);
        z[o] = acc;
      }
#pragma unroll
      for (int o = 0; o < 64; ++o) tile[t*65 + o] = z[o];
    }
    __syncthreads();
    // wave wvi reduces groups 2*wvi and 2*wvi+1; lane owns channel `lane`
#pragma unroll
    for (int i = 0; i < 2; ++i) {
      const int g = wvi*2 + i;
      float m = -1e30f, n = 1e30f, s = 0.f, q = 0.f;
#pragma unroll
      for (int k = 0; k < 32; ++k) {
        float v = tile[(g*32 + k)*65 + lane];
        m = fmaxf(m, v); n = fminf(n, v); s += v; q = fmaf(v, v, q);
      }
      const size_t group = (size_t)blockIdx.x*8 + g;
      kmx[group*128 + chunk*64 + lane] = m;
      kmn[group*128 + chunk*64 + lane] = n;
      gs[g][lane] = s; gq[g][lane] = q;
    }
    __syncthreads();
    if (t < 128) {
      const int c = t & 63;
      float tot = 0.f;
      if (t < 64) {
#pragma unroll
        for (int g = 0; g < 8; ++g) tot += gs[g][c];
        part[(size_t)blockIdx.x*256 + chunk*64 + c] = tot;
      } else {
#pragma unroll
        for (int g = 0; g < 8; ++g) tot += gq[g][c];
        part[(size_t)blockIdx.x*256 + 128 + chunk*64 + c] = tot;
      }
    }
    __syncthreads();
  }
}

// bn3 (r7-validated): out = relu(a*sel + b), sel = a>=0 ? kmax : kmin
// (max commutes with monotone affine+relu; sign of a picks the extreme).
__global__ __launch_bounds__(128) void bn3_kernel(const float* __restrict__ kmx,
                                                  const float* __restrict__ kmn,
                                                  const float* __restrict__ ab,
                                                  float* __restrict__ outp) {
  const int g = blockIdx.x;
  const int c = threadIdx.x;
  const float a = ab[c], bsh = ab[128 + c];
  const float v = (a >= 0.f) ? kmx[(size_t)g*128 + c] : kmn[(size_t)g*128 + c];
  outp[(size_t)g*128 + c] = fmaxf(0.f, fmaf(v, a, bsh));
}

// ============================ launcher ============================

extern "C" void kernel_launch(void* const* d_in, const int* in_sizes, int n_in,
                              void* d_out, int out_size, void* d_ws, size_t ws_size,
                              hipStream_t stream) {
  (void)in_sizes; (void)n_in; (void)out_size; (void)ws_size;
  const float* xyz = (const float*)d_in[0];
  const float* pts = (const float*)d_in[1];
  const float* w1  = (const float*)d_in[2];
  const float* b1  = (const float*)d_in[3];
  const float* g1  = (const float*)d_in[4];
  const float* be1 = (const float*)d_in[5];
  const float* w2  = (const float*)d_in[6];
  const float* b2  = (const float*)d_in[7];
  const float* g2  = (const float*)d_in[8];
  const float* be2 = (const float*)d_in[9];
  const float* w3  = (const float*)d_in[10];
  const float* b3  = (const float*)d_in[11];
  const float* g3  = (const float*)d_in[12];
  const float* be3 = (const float*)d_in[13];

  float* out = (float*)d_out;
  float* new_xyz    = out;
  float* new_points = out + NB*NS*3;

  // ws: x0 12.6MB | part 8.4MB | ab 2KB | z2u 67MB | kmx 8MB | kmn 8MB ~ 104MB
  // (ws >= 222MB proven in r9-r14 tierB runs — single path now)
  float* ws = (float*)d_ws;
  float* x0   = ws;                               // NR*6
  float* part = x0 + (size_t)NR*6;                // up to 2048*256 floats
  float* ab   = part + 2097152;                   // 512
  float* ab1  = ab;
  float* ab2  = ab + 128;
  float* ab3  = ab + 256;
  unsigned* z2u = (unsigned*)(ab + 512);          // NR*32 u32
  float* kmx = (float*)(z2u + (size_t)NR*32);     // 16384*128
  float* kmn = kmx + (size_t)16384*128;           // 16384*128
  const int NBLK = NR/256;                        // 2048

  hipLaunchKernelGGL(fps_kernel, dim3(NB), dim3(512), 0, stream, xyz, new_xyz);
  hipLaunchKernelGGL(ballquery_kernel, dim3(NB*NS/4), dim3(256), 0, stream, xyz, pts, new_xyz, x0);

  hipLaunchKernelGGL(stats1_kernel, dim3(NBLK), dim3(256), 0, stream, x0, w1, b1, part);
  hipLaunchKernelGGL(finalize_kernel, dim3(64), dim3(256), 0, stream, part, NBLK, 128, 64, g1, be1, ab1);
  hipLaunchKernelGGL(stats2_store, dim3(NBLK), dim3(256), 0, stream,
                     x0, w1, b1, ab1, w2, b2, z2u, part);
  hipLaunchKernelGGL(finalize_kernel, dim3(64), dim3(256), 0, stream, part, NBLK, 128, 64, g2, be2, ab2);
  hipLaunchKernelGGL(stats3_fused, dim3(NBLK), dim3(256), 0, stream,
                     z2u, ab2, w3, b3, part, kmx, kmn);
  hipLaunchKernelGGL(finalize_kernel, dim3(128), dim3(256), 0, stream, part, NBLK, 256, 128, g3, be3, ab3);
  hipLaunchKernelGGL(bn3_kernel, dim3(NB*NS), dim3(128), 0, stream, kmx, kmn, ab3, new_points);
}